// Round 1
// baseline (582.075 us; speedup 1.0000x reference)
//
#include <hip/hip_runtime.h>
#include <math.h>

#define HIDDEN 128
#define EDGE_DIM 16
#define N_HEADS 8
#define QK_SCALE 0.25f
#define LN_EPS 1e-5f

// ---------------------------------------------------------------------------
// Generic fp32 tiled GEMM: C[M,N] = A[M,K] @ W[K,N] + bias  (+ epilogue)
// EPI 0: +bias ; EPI 1: silu(+bias) ; EPI 2: +bias + residual R[M,N]
// 64x64 tile, BK=16, 256 threads, 4x4 micro-tile.
// ---------------------------------------------------------------------------
template <int EPI>
__global__ __launch_bounds__(256) void gemm_kernel(
    const float* __restrict__ A, const float* __restrict__ W,
    const float* __restrict__ bias, const float* __restrict__ R,
    float* __restrict__ C, int M, int N, int K) {
  __shared__ float As[16][68];  // As[k][m], padded stride
  __shared__ float Bs[16][68];  // Bs[k][n]

  const int tid = threadIdx.x;
  const int bm = blockIdx.x * 64;
  const int bn = blockIdx.y * 64;

  const int tm = (tid >> 4) << 2;  // micro-tile row base (0..60)
  const int tn = (tid & 15) << 2;  // micro-tile col base (0..60)

  const int ar = tid >> 2;         // A stage: row in tile 0..63
  const int ak = (tid & 3) << 2;   // A stage: k quad 0,4,8,12
  const int bk = tid >> 4;         // B stage: k row 0..15
  const int bc = (tid & 15) << 2;  // B stage: col quad

  float acc[4][4] = {};

  for (int k0 = 0; k0 < K; k0 += 16) {
    __syncthreads();
    float4 av = make_float4(0.f, 0.f, 0.f, 0.f);
    if (bm + ar < M) av = *(const float4*)(A + (size_t)(bm + ar) * K + k0 + ak);
    As[ak + 0][ar] = av.x;
    As[ak + 1][ar] = av.y;
    As[ak + 2][ar] = av.z;
    As[ak + 3][ar] = av.w;
    *(float4*)&Bs[bk][bc] = *(const float4*)(W + (size_t)(k0 + bk) * N + bn + bc);
    __syncthreads();

#pragma unroll
    for (int kk = 0; kk < 16; ++kk) {
      float4 a = *(const float4*)&As[kk][tm];
      float4 b = *(const float4*)&Bs[kk][tn];
      float a4[4] = {a.x, a.y, a.z, a.w};
      float b4[4] = {b.x, b.y, b.z, b.w};
#pragma unroll
      for (int i = 0; i < 4; ++i)
#pragma unroll
        for (int j = 0; j < 4; ++j) acc[i][j] = fmaf(a4[i], b4[j], acc[i][j]);
    }
  }

  const int col = bn + tn;
  float4 bias4 = *(const float4*)(bias + col);
#pragma unroll
  for (int i = 0; i < 4; ++i) {
    int row = bm + tm + i;
    if (row < M) {
      float o[4] = {acc[i][0] + bias4.x, acc[i][1] + bias4.y,
                    acc[i][2] + bias4.z, acc[i][3] + bias4.w};
      if (EPI == 1) {
#pragma unroll
        for (int j = 0; j < 4; ++j) o[j] = o[j] / (1.f + __expf(-o[j]));
      }
      if (EPI == 2) {
        float4 r4 = *(const float4*)(R + (size_t)row * N + col);
        o[0] += r4.x; o[1] += r4.y; o[2] += r4.z; o[3] += r4.w;
      }
      *(float4*)(C + (size_t)row * N + col) = make_float4(o[0], o[1], o[2], o[3]);
    }
  }
}

// ---------------------------------------------------------------------------
// Edge bias MLP: eb[e,h] = silu(ef @ Wb1 + bb1) @ Wb2 + bb2
// ---------------------------------------------------------------------------
__global__ __launch_bounds__(256) void edge_bias_kernel(
    const float* __restrict__ ef, const float* __restrict__ Wb1,
    const float* __restrict__ bb1, const float* __restrict__ Wb2,
    const float* __restrict__ bb2, float* __restrict__ eb, int E) {
  __shared__ float w1[128], w2[64], b1[8], b2[8];
  int tid = threadIdx.x;
  if (tid < 128) w1[tid] = Wb1[tid];
  else if (tid < 192) w2[tid - 128] = Wb2[tid - 128];
  else if (tid < 200) b1[tid - 192] = bb1[tid - 192];
  else if (tid < 208) b2[tid - 200] = bb2[tid - 200];
  __syncthreads();

  int e = blockIdx.x * 256 + tid;
  if (e >= E) return;

  const float4* p4 = (const float4*)(ef + (size_t)e * 16);
  float4 f0 = p4[0], f1 = p4[1], f2 = p4[2], f3 = p4[3];
  float x[16] = {f0.x, f0.y, f0.z, f0.w, f1.x, f1.y, f1.z, f1.w,
                 f2.x, f2.y, f2.z, f2.w, f3.x, f3.y, f3.z, f3.w};

  float h[8];
#pragma unroll
  for (int j = 0; j < 8; ++j) h[j] = b1[j];
#pragma unroll
  for (int i = 0; i < 16; ++i) {
    float xi = x[i];
#pragma unroll
    for (int j = 0; j < 8; ++j) h[j] = fmaf(xi, w1[i * 8 + j], h[j]);
  }
#pragma unroll
  for (int j = 0; j < 8; ++j) h[j] = h[j] / (1.f + __expf(-h[j]));

  float o[8];
#pragma unroll
  for (int j = 0; j < 8; ++j) o[j] = b2[j];
#pragma unroll
  for (int jj = 0; jj < 8; ++jj) {
    float hj = h[jj];
#pragma unroll
    for (int j = 0; j < 8; ++j) o[j] = fmaf(hj, w2[jj * 8 + j], o[j]);
  }
  float4* op = (float4*)(eb + (size_t)e * 8);
  op[0] = make_float4(o[0], o[1], o[2], o[3]);
  op[1] = make_float4(o[4], o[5], o[6], o[7]);
}

// ---------------------------------------------------------------------------
// CSR build: histogram -> scan -> scatter (edge ids)
// ---------------------------------------------------------------------------
__global__ void hist_kernel(const int* __restrict__ dst, int* __restrict__ counts, int E) {
  int e = blockIdx.x * blockDim.x + threadIdx.x;
  if (e < E) atomicAdd(&counts[dst[e]], 1);
}

__global__ __launch_bounds__(1024) void scan_kernel(const int* __restrict__ counts,
                                                    int* __restrict__ offsets, int N, int E) {
  __shared__ int wsum[16];
  __shared__ int s_carry;
  int tid = threadIdx.x;
  int lane = tid & 63, wid = tid >> 6;
  if (tid == 0) s_carry = 0;
  __syncthreads();
  int nchunks = (N + 1023) / 1024;
  for (int c = 0; c < nchunks; ++c) {
    int i = c * 1024 + tid;
    int x = (i < N) ? counts[i] : 0;
    int incl = x;
#pragma unroll
    for (int off = 1; off < 64; off <<= 1) {
      int y = __shfl_up(incl, off, 64);
      if (lane >= off) incl += y;
    }
    if (lane == 63) wsum[wid] = incl;
    __syncthreads();
    if (wid == 0) {
      int w = (lane < 16) ? wsum[lane] : 0;
#pragma unroll
      for (int off = 1; off < 16; off <<= 1) {
        int y = __shfl_up(w, off, 64);
        if (lane >= off) w += y;
      }
      if (lane < 16) wsum[lane] = w;
    }
    __syncthreads();
    int wprefix = (wid > 0) ? wsum[wid - 1] : 0;
    int chunk_total = wsum[15];
    if (i < N) offsets[i] = s_carry + wprefix + incl - x;
    __syncthreads();
    if (tid == 0) s_carry += chunk_total;
    __syncthreads();
  }
  if (tid == 0) offsets[N] = E;
}

__global__ void scatter_kernel(const int* __restrict__ dst, const int* __restrict__ offsets,
                               int* __restrict__ cursor, int* __restrict__ eid_csr, int E) {
  int e = blockIdx.x * blockDim.x + threadIdx.x;
  if (e >= E) return;
  int d = dst[e];
  int p = offsets[d] + atomicAdd(&cursor[d], 1);
  eid_csr[p] = e;
}

// ---------------------------------------------------------------------------
// Per-dst-node online-softmax attention + aggregation.
// Block = 128 threads = one node. thread t owns output col t, head h=t>>4.
// ---------------------------------------------------------------------------
__global__ __launch_bounds__(128) void node_attn_kernel(
    const float* __restrict__ q, const float* __restrict__ k,
    const float* __restrict__ v, const int* __restrict__ srcA,
    const float* __restrict__ eb, const int* __restrict__ eid_csr,
    const int* __restrict__ offsets, float* __restrict__ agg) {
  int n = blockIdx.x;
  int t = threadIdx.x;
  int h = t >> 4;

  float qv = q[(size_t)n * HIDDEN + t] * QK_SCALE;
  int s0 = offsets[n], s1 = offsets[n + 1];

  float m = -INFINITY, l = 0.f, acc = 0.f;
  for (int p = s0; p < s1; ++p) {
    int eid = eid_csr[p];
    int s = srcA[eid];
    float kv = k[(size_t)s * HIDDEN + t];
    float vv = v[(size_t)s * HIDDEN + t];
    float prod = qv * kv;
#pragma unroll
    for (int off = 1; off < 16; off <<= 1) prod += __shfl_xor(prod, off, 64);
    float logit = prod + eb[(size_t)eid * N_HEADS + h];
    float mnew = fmaxf(m, logit);
    float f = __expf(m - mnew);  // first iter: exp(-inf)=0
    float pe = __expf(logit - mnew);
    l = l * f + pe;
    acc = acc * f + pe * vv;
    m = mnew;
  }
  agg[(size_t)n * HIDDEN + t] = (l > 0.f) ? acc / l : 0.f;
}

// ---------------------------------------------------------------------------
// Row LayerNorm over 128 cols. 1 wave per row, 4 rows per block.
// ---------------------------------------------------------------------------
__global__ __launch_bounds__(256) void ln_kernel(const float* __restrict__ x,
                                                 const float* __restrict__ g,
                                                 const float* __restrict__ be,
                                                 float* __restrict__ y, int M) {
  int row = blockIdx.x * 4 + (threadIdx.x >> 6);
  int lane = threadIdx.x & 63;
  if (row >= M) return;
  float2 xv = *(const float2*)(x + (size_t)row * HIDDEN + lane * 2);
  float s = xv.x + xv.y;
  float sq = xv.x * xv.x + xv.y * xv.y;
#pragma unroll
  for (int off = 1; off < 64; off <<= 1) {
    s += __shfl_xor(s, off, 64);
    sq += __shfl_xor(sq, off, 64);
  }
  float mean = s * (1.f / 128.f);
  float var = sq * (1.f / 128.f) - mean * mean;
  float r = rsqrtf(var + LN_EPS);
  float2 gv = *(const float2*)(g + lane * 2);
  float2 bv = *(const float2*)(be + lane * 2);
  float2 yv;
  yv.x = (xv.x - mean) * r * gv.x + bv.x;
  yv.y = (xv.y - mean) * r * gv.y + bv.y;
  *(float2*)(y + (size_t)row * HIDDEN + lane * 2) = yv;
}

// ---------------------------------------------------------------------------
extern "C" void kernel_launch(void* const* d_in, const int* in_sizes, int n_in,
                              void* d_out, int out_size, void* d_ws, size_t ws_size,
                              hipStream_t stream) {
  const float* nf = (const float*)d_in[0];
  const int* ei = (const int*)d_in[1];
  const float* ef = (const float*)d_in[2];
  const float* Wq = (const float*)d_in[3];
  const float* bq = (const float*)d_in[4];
  const float* Wk = (const float*)d_in[5];
  const float* bk_ = (const float*)d_in[6];
  const float* Wv = (const float*)d_in[7];
  const float* bv = (const float*)d_in[8];
  const float* Wb1 = (const float*)d_in[9];
  const float* bb1 = (const float*)d_in[10];
  const float* Wb2 = (const float*)d_in[11];
  const float* bb2 = (const float*)d_in[12];
  const float* Wo = (const float*)d_in[13];
  const float* bo = (const float*)d_in[14];
  const float* Wf1 = (const float*)d_in[15];
  const float* bf1 = (const float*)d_in[16];
  const float* Wf2 = (const float*)d_in[17];
  const float* bf2 = (const float*)d_in[18];
  const float* g1 = (const float*)d_in[19];
  const float* be1 = (const float*)d_in[20];
  const float* g2 = (const float*)d_in[21];
  const float* be2 = (const float*)d_in[22];

  const int N = in_sizes[0] / HIDDEN;
  const int E = in_sizes[2] / EDGE_DIM;
  const int* srcA = ei;
  const int* dstA = ei + E;

  float* ws = (float*)d_ws;
  size_t off = 0;
  auto alloc = [&](size_t elems) {
    float* p = ws + off;
    off += (elems + 3) & ~(size_t)3;
    return p;
  };
  float* q = alloc((size_t)N * HIDDEN);
  float* k = alloc((size_t)N * HIDDEN);
  float* v = alloc((size_t)N * HIDDEN);  // contiguous after k
  float* eb = alloc((size_t)E * N_HEADS);
  int* eid_csr = (int*)alloc(E);
  int* counts = (int*)alloc(N);
  int* offs = (int*)alloc(N + 1);
  int* cursor = (int*)alloc(N);
  float* agg = alloc((size_t)N * HIDDEN);

  // buffer reuse (all strictly after producers are dead):
  float* t1 = eb;    // attn-out pre-LN          (eb dead after node_attn)
  float* x1 = q;     // LN1 output               (q dead after node_attn)
  float* hbuf = k;   // FFN hidden [N,256] spans k..v (dead after node_attn)
  float* t2 = agg;   // FFN out pre-LN           (agg dead after Wo GEMM)
  float* outp = (float*)d_out;

  const int gm = (N + 63) / 64;
  const int eblocks = (E + 255) / 256;

  // QKV projections
  gemm_kernel<0><<<dim3(gm, 2), 256, 0, stream>>>(nf, Wq, bq, nullptr, q, N, HIDDEN, HIDDEN);
  gemm_kernel<0><<<dim3(gm, 2), 256, 0, stream>>>(nf, Wk, bk_, nullptr, k, N, HIDDEN, HIDDEN);
  gemm_kernel<0><<<dim3(gm, 2), 256, 0, stream>>>(nf, Wv, bv, nullptr, v, N, HIDDEN, HIDDEN);

  // edge bias MLP
  edge_bias_kernel<<<eblocks, 256, 0, stream>>>(ef, Wb1, bb1, Wb2, bb2, eb, E);

  // CSR build
  hipMemsetAsync(counts, 0, (size_t)N * sizeof(int), stream);
  hipMemsetAsync(cursor, 0, (size_t)N * sizeof(int), stream);
  hist_kernel<<<eblocks, 256, 0, stream>>>(dstA, counts, E);
  scan_kernel<<<1, 1024, 0, stream>>>(counts, offs, N, E);
  scatter_kernel<<<eblocks, 256, 0, stream>>>(dstA, offs, cursor, eid_csr, E);

  // per-node online-softmax attention + aggregation
  node_attn_kernel<<<N, 128, 0, stream>>>(q, k, v, srcA, eb, eid_csr, offs, agg);

  // attn out proj + residual, LN1
  gemm_kernel<2><<<dim3(gm, 2), 256, 0, stream>>>(agg, Wo, bo, nf, t1, N, HIDDEN, HIDDEN);
  ln_kernel<<<(N + 3) / 4, 256, 0, stream>>>(t1, g1, be1, x1, N);

  // FFN
  gemm_kernel<1><<<dim3(gm, 4), 256, 0, stream>>>(x1, Wf1, bf1, nullptr, hbuf, N, 256, HIDDEN);
  gemm_kernel<2><<<dim3(gm, 2), 256, 0, stream>>>(hbuf, Wf2, bf2, x1, t2, N, HIDDEN, 256);
  ln_kernel<<<(N + 3) / 4, 256, 0, stream>>>(t2, g2, be2, outp, N);
}

// Round 2
// 367.925 us; speedup vs baseline: 1.5820x; 1.5820x over previous
//
#include <hip/hip_runtime.h>
#include <hip/hip_bf16.h>
#include <math.h>

#define HIDDEN 128
#define EDGE_DIM 16
#define N_HEADS 8
#define QK_SCALE 0.25f
#define LN_EPS 1e-5f

using bf16x8 = __attribute__((ext_vector_type(8))) short;
using f32x4 = __attribute__((ext_vector_type(4))) float;
typedef __hip_bfloat16 bf16;

// ---------------------------------------------------------------------------
// fp32 -> bf16 row-major convert
// ---------------------------------------------------------------------------
__global__ __launch_bounds__(256) void conv_bf16_kernel(const float* __restrict__ in,
                                                        bf16* __restrict__ out, size_t n) {
  size_t i = ((size_t)blockIdx.x * 256 + threadIdx.x) * 4;
  if (i >= n) return;
  float4 v = *(const float4*)(in + i);
  out[i + 0] = __float2bfloat16(v.x);
  out[i + 1] = __float2bfloat16(v.y);
  out[i + 2] = __float2bfloat16(v.z);
  out[i + 3] = __float2bfloat16(v.w);
}

// ---------------------------------------------------------------------------
// Weight prep: transposed bf16 copies [N][K], fused qkv bias.
// ---------------------------------------------------------------------------
__global__ __launch_bounds__(256) void conv_weights_kernel(
    const float* __restrict__ Wq, const float* __restrict__ Wk, const float* __restrict__ Wv,
    const float* __restrict__ bq, const float* __restrict__ bk, const float* __restrict__ bv,
    const float* __restrict__ Wo, const float* __restrict__ Wf1, const float* __restrict__ Wf2,
    bf16* __restrict__ Wqkv_t, bf16* __restrict__ Wo_t, bf16* __restrict__ Wf1_t,
    bf16* __restrict__ Wf2_t, float* __restrict__ bqkv) {
  int i = blockIdx.x * 256 + threadIdx.x;
  if (i < 49152) {  // Wqkv_t [384][128]
    int n = i >> 7, k = i & 127;
    const float* W = (n < 128) ? Wq : ((n < 256) ? Wk : Wv);
    int nn = n & 127;
    Wqkv_t[i] = __float2bfloat16(W[k * 128 + nn]);
  } else if (i < 65536) {  // Wo_t [128][128]
    int j = i - 49152;
    int n = j >> 7, k = j & 127;
    Wo_t[j] = __float2bfloat16(Wo[k * 128 + n]);
  } else if (i < 98304) {  // Wf1_t [256][128]
    int j = i - 65536;
    int n = j >> 7, k = j & 127;
    Wf1_t[j] = __float2bfloat16(Wf1[k * 256 + n]);
  } else if (i < 131072) {  // Wf2_t [128][256]
    int j = i - 98304;
    int n = j >> 8, k = j & 255;
    Wf2_t[j] = __float2bfloat16(Wf2[k * 128 + n]);
  }
  if (i < 384) bqkv[i] = (i < 128) ? bq[i] : ((i < 256) ? bk[i - 128] : bv[i - 256]);
}

// ---------------------------------------------------------------------------
// LDS-free MFMA GEMM. C[M,Nc] = A[M,K](bf16) @ Wt^T + bias (+ epilogue).
// Wt is [Nc][K] bf16 (pre-transposed). Block 256 thr = 4 waves; wave w owns
// rows [bm+32w, bm+32w+32), block owns cols [bn, bn+64). K in {128, 256}.
// EPI 0: none; 1: silu; 2: +R. OUTBF: write bf16 else fp32.
// ---------------------------------------------------------------------------
template <int K, int EPI, int OUTBF>
__global__ __launch_bounds__(256) void mfma_gemm_kernel(
    const bf16* __restrict__ A, const bf16* __restrict__ Wt,
    const float* __restrict__ bias, const float* __restrict__ R,
    void* __restrict__ Cout, int M, int Nc) {
  const int tid = threadIdx.x;
  const int w = tid >> 6, l = tid & 63;
  const int lr = l & 15;  // row-in-frag (A) / col-in-frag (B,C)
  const int lk = l >> 4;  // k sub-block 0..3
  const int bm = blockIdx.x * 128, bn = blockIdx.y * 64;

  f32x4 acc[2][4] = {};
  const int arow0 = bm + w * 32 + lr;

  for (int k0 = 0; k0 < K; k0 += 128) {
    bf16x8 bfr[4][4];
#pragma unroll
    for (int fn = 0; fn < 4; ++fn) {
      const bf16* wp = Wt + (size_t)(bn + fn * 16 + lr) * K + k0 + lk * 8;
#pragma unroll
      for (int ks = 0; ks < 4; ++ks) bfr[fn][ks] = *(const bf16x8*)(wp + ks * 32);
    }
    bf16x8 afr[2][4];
#pragma unroll
    for (int fr = 0; fr < 2; ++fr) {
      int row = arow0 + fr * 16;
      if (row >= M) row = M - 1;
      const bf16* ap = A + (size_t)row * K + k0 + lk * 8;
#pragma unroll
      for (int ks = 0; ks < 4; ++ks) afr[fr][ks] = *(const bf16x8*)(ap + ks * 32);
    }
#pragma unroll
    for (int ks = 0; ks < 4; ++ks)
#pragma unroll
      for (int fr = 0; fr < 2; ++fr)
#pragma unroll
        for (int fn = 0; fn < 4; ++fn)
          acc[fr][fn] = __builtin_amdgcn_mfma_f32_16x16x32_bf16(afr[fr][ks], bfr[fn][ks],
                                                                acc[fr][fn], 0, 0, 0);
  }

#pragma unroll
  for (int fn = 0; fn < 4; ++fn) {
    const int col = bn + fn * 16 + lr;
    const float bv = bias[col];
#pragma unroll
    for (int fr = 0; fr < 2; ++fr) {
      const int rbase = bm + w * 32 + fr * 16 + lk * 4;
#pragma unroll
      for (int r = 0; r < 4; ++r) {
        int row = rbase + r;
        if (row < M) {
          float o = acc[fr][fn][r] + bv;
          if (EPI == 1) o = o / (1.f + __expf(-o));
          if (EPI == 2) o += R[(size_t)row * Nc + col];
          if (OUTBF)
            ((bf16*)Cout)[(size_t)row * Nc + col] = __float2bfloat16(o);
          else
            ((float*)Cout)[(size_t)row * Nc + col] = o;
        }
      }
    }
  }
}

// ---------------------------------------------------------------------------
// Edge bias MLP (fp32, unchanged)
// ---------------------------------------------------------------------------
__global__ __launch_bounds__(256) void edge_bias_kernel(
    const float* __restrict__ ef, const float* __restrict__ Wb1,
    const float* __restrict__ bb1, const float* __restrict__ Wb2,
    const float* __restrict__ bb2, float* __restrict__ eb, int E) {
  __shared__ float w1[128], w2[64], b1[8], b2[8];
  int tid = threadIdx.x;
  if (tid < 128) w1[tid] = Wb1[tid];
  else if (tid < 192) w2[tid - 128] = Wb2[tid - 128];
  else if (tid < 200) b1[tid - 192] = bb1[tid - 192];
  else if (tid < 208) b2[tid - 200] = bb2[tid - 200];
  __syncthreads();

  int e = blockIdx.x * 256 + tid;
  if (e >= E) return;

  const float4* p4 = (const float4*)(ef + (size_t)e * 16);
  float4 f0 = p4[0], f1 = p4[1], f2 = p4[2], f3 = p4[3];
  float x[16] = {f0.x, f0.y, f0.z, f0.w, f1.x, f1.y, f1.z, f1.w,
                 f2.x, f2.y, f2.z, f2.w, f3.x, f3.y, f3.z, f3.w};

  float h[8];
#pragma unroll
  for (int j = 0; j < 8; ++j) h[j] = b1[j];
#pragma unroll
  for (int i = 0; i < 16; ++i) {
    float xi = x[i];
#pragma unroll
    for (int j = 0; j < 8; ++j) h[j] = fmaf(xi, w1[i * 8 + j], h[j]);
  }
#pragma unroll
  for (int j = 0; j < 8; ++j) h[j] = h[j] / (1.f + __expf(-h[j]));

  float o[8];
#pragma unroll
  for (int j = 0; j < 8; ++j) o[j] = b2[j];
#pragma unroll
  for (int jj = 0; jj < 8; ++jj) {
    float hj = h[jj];
#pragma unroll
    for (int j = 0; j < 8; ++j) o[j] = fmaf(hj, w2[jj * 8 + j], o[j]);
  }
  float4* op = (float4*)(eb + (size_t)e * 8);
  op[0] = make_float4(o[0], o[1], o[2], o[3]);
  op[1] = make_float4(o[4], o[5], o[6], o[7]);
}

// ---------------------------------------------------------------------------
// CSR build: histogram -> parallel 3-kernel scan -> scatter
// ---------------------------------------------------------------------------
__global__ void hist_kernel(const int* __restrict__ dst, int* __restrict__ counts, int E) {
  int e = blockIdx.x * blockDim.x + threadIdx.x;
  if (e < E) atomicAdd(&counts[dst[e]], 1);
}

__device__ __forceinline__ int wave_incl_scan(int x, int lane) {
  int incl = x;
#pragma unroll
  for (int off = 1; off < 64; off <<= 1) {
    int y = __shfl_up(incl, off, 64);
    if (lane >= off) incl += y;
  }
  return incl;
}

__global__ __launch_bounds__(256) void scan_block_kernel(const int* __restrict__ counts,
                                                         int* __restrict__ offs,
                                                         int* __restrict__ btot, int N) {
  __shared__ int s4[4];
  int tid = threadIdx.x;
  int i = blockIdx.x * 256 + tid;
  int lane = tid & 63, wv = tid >> 6;
  int x = (i < N) ? counts[i] : 0;
  int incl = wave_incl_scan(x, lane);
  if (lane == 63) s4[wv] = incl;
  __syncthreads();
  if (tid == 0) {
    int s = 0;
#pragma unroll
    for (int j = 0; j < 4; ++j) { int t = s4[j]; s4[j] = s; s += t; }
    btot[blockIdx.x] = s;
  }
  __syncthreads();
  if (i < N) offs[i] = s4[wv] + incl - x;
}

__global__ __launch_bounds__(256) void scan_tot_kernel(int* __restrict__ btot, int nb) {
  __shared__ int s4[4];
  __shared__ int carry;
  int tid = threadIdx.x;
  int lane = tid & 63, wv = tid >> 6;
  if (tid == 0) carry = 0;
  __syncthreads();
  for (int c0 = 0; c0 < nb; c0 += 256) {
    int i = c0 + tid;
    int x = (i < nb) ? btot[i] : 0;
    int incl = wave_incl_scan(x, lane);
    if (lane == 63) s4[wv] = incl;
    __syncthreads();
    if (tid == 0) {
      int s = 0;
#pragma unroll
      for (int j = 0; j < 4; ++j) { int t = s4[j]; s4[j] = s; s += t; }
      s4[0] += 0;  // keep
    }
    __syncthreads();
    int base = carry + s4[wv];
    if (i < nb) btot[i] = base + incl - x;
    __syncthreads();
    if (tid == 255) carry = base + incl;  // carry += chunk total
    __syncthreads();
  }
}

__global__ __launch_bounds__(256) void scan_add_kernel(int* __restrict__ offs,
                                                       const int* __restrict__ btot,
                                                       int N, int E) {
  int i = blockIdx.x * 256 + threadIdx.x;
  if (i < N) offs[i] += btot[blockIdx.x];
  if (i == 0) offs[N] = E;
}

__global__ void scatter_kernel(const int* __restrict__ dst, const int* __restrict__ src,
                               const int* __restrict__ offs, int* __restrict__ cursor,
                               int* __restrict__ eid_csr, int* __restrict__ src_csr, int E) {
  int e = blockIdx.x * blockDim.x + threadIdx.x;
  if (e >= E) return;
  int d = dst[e];
  int p = offs[d] + atomicAdd(&cursor[d], 1);
  eid_csr[p] = e;
  src_csr[p] = src[e];
}

// ---------------------------------------------------------------------------
// Attention: 1 wave per dst node, 4 nodes per block. Lane owns cols 2l,2l+1.
// qkv row: [q(128) | k(128) | v(128)] bf16, stride 384.
// ---------------------------------------------------------------------------
__global__ __launch_bounds__(256) void node_attn_kernel(
    const bf16* __restrict__ qkv, const int* __restrict__ src_csr,
    const float* __restrict__ eb, const int* __restrict__ eid_csr,
    const int* __restrict__ offs, bf16* __restrict__ agg, int Nn) {
  int n = blockIdx.x * 4 + (threadIdx.x >> 6);
  int l = threadIdx.x & 63;
  if (n >= Nn) return;
  const int h = l >> 3;  // head of cols 2l, 2l+1

  __hip_bfloat162 q2 = *(const __hip_bfloat162*)(qkv + (size_t)n * 384 + 2 * l);
  float qx = __bfloat162float(q2.x) * QK_SCALE;
  float qy = __bfloat162float(q2.y) * QK_SCALE;

  int s0 = offs[n], s1 = offs[n + 1];
  float m = -INFINITY, lsum = 0.f, a0 = 0.f, a1 = 0.f;

  int eid = 0, s = 0;
  if (s0 < s1) { eid = eid_csr[s0]; s = src_csr[s0]; }
  for (int p = s0; p < s1; ++p) {
    int neid = eid, ns = s;
    if (p + 1 < s1) { neid = eid_csr[p + 1]; ns = src_csr[p + 1]; }
    const bf16* kvrow = qkv + (size_t)s * 384 + 128;
    __hip_bfloat162 k2 = *(const __hip_bfloat162*)(kvrow + 2 * l);
    __hip_bfloat162 v2 = *(const __hip_bfloat162*)(kvrow + 128 + 2 * l);
    float ebv = eb[(size_t)eid * N_HEADS + h];
    float prod = qx * __bfloat162float(k2.x) + qy * __bfloat162float(k2.y);
#pragma unroll
    for (int off = 1; off < 8; off <<= 1) prod += __shfl_xor(prod, off, 64);
    float logit = prod + ebv;
    float mnew = fmaxf(m, logit);
    float f = __expf(m - mnew);  // first iter: exp(-inf)=0
    float pe = __expf(logit - mnew);
    lsum = lsum * f + pe;
    a0 = a0 * f + pe * __bfloat162float(v2.x);
    a1 = a1 * f + pe * __bfloat162float(v2.y);
    m = mnew;
    eid = neid; s = ns;
  }
  float inv = (lsum > 0.f) ? 1.f / lsum : 0.f;
  __hip_bfloat162 o2;
  o2.x = __float2bfloat16(a0 * inv);
  o2.y = __float2bfloat16(a1 * inv);
  *(__hip_bfloat162*)(agg + (size_t)n * HIDDEN + 2 * l) = o2;
}

// ---------------------------------------------------------------------------
// Row LayerNorm (128 cols). 1 wave/row, 4 rows/block. Optional bf16 copy out.
// ---------------------------------------------------------------------------
__global__ __launch_bounds__(256) void ln_kernel(const float* __restrict__ x,
                                                 const float* __restrict__ g,
                                                 const float* __restrict__ be,
                                                 float* __restrict__ y,
                                                 bf16* __restrict__ yb, int M) {
  int row = blockIdx.x * 4 + (threadIdx.x >> 6);
  int lane = threadIdx.x & 63;
  if (row >= M) return;
  float2 xv = *(const float2*)(x + (size_t)row * HIDDEN + lane * 2);
  float s = xv.x + xv.y;
  float sq = xv.x * xv.x + xv.y * xv.y;
#pragma unroll
  for (int off = 1; off < 64; off <<= 1) {
    s += __shfl_xor(s, off, 64);
    sq += __shfl_xor(sq, off, 64);
  }
  float mean = s * (1.f / 128.f);
  float var = sq * (1.f / 128.f) - mean * mean;
  float r = rsqrtf(var + LN_EPS);
  float2 gv = *(const float2*)(g + lane * 2);
  float2 bv = *(const float2*)(be + lane * 2);
  float2 yv;
  yv.x = (xv.x - mean) * r * gv.x + bv.x;
  yv.y = (xv.y - mean) * r * gv.y + bv.y;
  if (y) *(float2*)(y + (size_t)row * HIDDEN + lane * 2) = yv;
  if (yb) {
    __hip_bfloat162 h2;
    h2.x = __float2bfloat16(yv.x);
    h2.y = __float2bfloat16(yv.y);
    *(__hip_bfloat162*)(yb + (size_t)row * HIDDEN + lane * 2) = h2;
  }
}

// ---------------------------------------------------------------------------
extern "C" void kernel_launch(void* const* d_in, const int* in_sizes, int n_in,
                              void* d_out, int out_size, void* d_ws, size_t ws_size,
                              hipStream_t stream) {
  const float* nf = (const float*)d_in[0];
  const int* ei = (const int*)d_in[1];
  const float* ef = (const float*)d_in[2];
  const float* Wq = (const float*)d_in[3];
  const float* bq = (const float*)d_in[4];
  const float* Wk = (const float*)d_in[5];
  const float* bk_ = (const float*)d_in[6];
  const float* Wv = (const float*)d_in[7];
  const float* bv = (const float*)d_in[8];
  const float* Wb1 = (const float*)d_in[9];
  const float* bb1 = (const float*)d_in[10];
  const float* Wb2 = (const float*)d_in[11];
  const float* bb2 = (const float*)d_in[12];
  const float* Wo = (const float*)d_in[13];
  const float* bo = (const float*)d_in[14];
  const float* Wf1 = (const float*)d_in[15];
  const float* bf1 = (const float*)d_in[16];
  const float* Wf2 = (const float*)d_in[17];
  const float* bf2 = (const float*)d_in[18];
  const float* g1 = (const float*)d_in[19];
  const float* be1 = (const float*)d_in[20];
  const float* g2 = (const float*)d_in[21];
  const float* be2 = (const float*)d_in[22];

  const int N = in_sizes[0] / HIDDEN;
  const int E = in_sizes[2] / EDGE_DIM;
  const int* srcA = ei;
  const int* dstA = ei + E;

  char* base = (char*)d_ws;
  size_t off = 0;
  auto alloc = [&](size_t bytes) {
    off = (off + 255) & ~(size_t)255;
    char* p = base + off;
    off += bytes;
    return p;
  };

  // region A: nf_bf16 [N,128] -> x1b [N,128] bf16
  bf16* nf16 = (bf16*)alloc((size_t)N * HIDDEN * 2);
  bf16* x1b = nf16;
  // region B: qkv [N,384] bf16 -> hbuf [N,256] bf16
  bf16* qkv = (bf16*)alloc((size_t)N * 384 * 2);
  bf16* hbuf = qkv;
  // region C: eb [E,8] f32 -> t1 [N,128] f32 -> t2 [N,128] f32
  size_t regC = (size_t)E * N_HEADS * 4;
  size_t t1b = (size_t)N * HIDDEN * 4;
  float* eb = (float*)alloc(regC > t1b ? regC : t1b);
  float* t1 = eb;
  float* t2 = eb;
  // standalone
  bf16* agg = (bf16*)alloc((size_t)N * HIDDEN * 2);
  float* x1 = (float*)alloc((size_t)N * HIDDEN * 4);
  int* eid_csr = (int*)alloc((size_t)E * 4);
  int* src_csr = (int*)alloc((size_t)E * 4);
  int* counts = (int*)alloc((size_t)N * 4);
  int* offs = (int*)alloc((size_t)(N + 1) * 4);
  int* cursor = (int*)alloc((size_t)N * 4);
  const int nb = (N + 255) / 256;
  int* btot = (int*)alloc((size_t)nb * 4);
  // weights
  bf16* Wqkv_t = (bf16*)alloc(384 * 128 * 2);
  bf16* Wo_t = (bf16*)alloc(128 * 128 * 2);
  bf16* Wf1_t = (bf16*)alloc(256 * 128 * 2);
  bf16* Wf2_t = (bf16*)alloc(128 * 256 * 2);
  float* bqkv = (float*)alloc(384 * 4);

  float* outp = (float*)d_out;
  const int mb = (N + 127) / 128;
  const int eblocks = (E + 255) / 256;

  // prep
  conv_bf16_kernel<<<((size_t)N * HIDDEN / 4 + 255) / 256, 256, 0, stream>>>(
      nf, nf16, (size_t)N * HIDDEN);
  conv_weights_kernel<<<512, 256, 0, stream>>>(Wq, Wk, Wv, bq, bk_, bv, Wo, Wf1, Wf2,
                                               Wqkv_t, Wo_t, Wf1_t, Wf2_t, bqkv);

  // fused QKV projection -> qkv bf16 [N][q|k|v]
  mfma_gemm_kernel<128, 0, 1><<<dim3(mb, 6), 256, 0, stream>>>(
      nf16, Wqkv_t, bqkv, nullptr, qkv, N, 384);

  // edge bias MLP
  edge_bias_kernel<<<eblocks, 256, 0, stream>>>(ef, Wb1, bb1, Wb2, bb2, eb, E);

  // CSR build
  hipMemsetAsync(counts, 0, (size_t)N * 4, stream);
  hipMemsetAsync(cursor, 0, (size_t)N * 4, stream);
  hist_kernel<<<eblocks, 256, 0, stream>>>(dstA, counts, E);
  scan_block_kernel<<<nb, 256, 0, stream>>>(counts, offs, btot, N);
  scan_tot_kernel<<<1, 256, 0, stream>>>(btot, nb);
  scan_add_kernel<<<nb, 256, 0, stream>>>(offs, btot, N, E);
  scatter_kernel<<<eblocks, 256, 0, stream>>>(dstA, srcA, offs, cursor, eid_csr, src_csr, E);

  // attention + aggregation (bf16 gather, fp32 math)
  node_attn_kernel<<<(N + 3) / 4, 256, 0, stream>>>(qkv, src_csr, eb, eid_csr, offs, agg, N);

  // out proj + residual, LN1 (fp32 + bf16 copies)
  mfma_gemm_kernel<128, 2, 0><<<dim3(mb, 2), 256, 0, stream>>>(
      agg, Wo_t, bo, nf, t1, N, 128);
  ln_kernel<<<(N + 3) / 4, 256, 0, stream>>>(t1, g1, be1, x1, x1b, N);

  // FFN
  mfma_gemm_kernel<128, 1, 1><<<dim3(mb, 4), 256, 0, stream>>>(
      x1b, Wf1_t, bf1, nullptr, hbuf, N, 256);
  mfma_gemm_kernel<256, 2, 0><<<dim3(mb, 2), 256, 0, stream>>>(
      hbuf, Wf2_t, bf2, x1, t2, N, 128);
  ln_kernel<<<(N + 3) / 4, 256, 0, stream>>>(t2, g2, be2, outp, nullptr, N);
}

// Round 3
// 352.246 us; speedup vs baseline: 1.6525x; 1.0445x over previous
//
#include <hip/hip_runtime.h>
#include <hip/hip_bf16.h>
#include <math.h>

#define HIDDEN 128
#define EDGE_DIM 16
#define N_HEADS 8
#define QK_SCALE 0.25f
#define LN_EPS 1e-5f

using bf16x8 = __attribute__((ext_vector_type(8))) short;
using f32x4 = __attribute__((ext_vector_type(4))) float;
typedef __hip_bfloat16 bf16;

__device__ __forceinline__ float b2f(short u) {
  union { unsigned int i; float f; } c;
  c.i = ((unsigned int)(unsigned short)u) << 16;
  return c.f;
}
__device__ __forceinline__ short f2b(float f) {
  bf16 h = __float2bfloat16(f);
  union { bf16 b; short s; } c;
  c.b = h;
  return c.s;
}

// ---------------------------------------------------------------------------
// Weight prep: transposed bf16 copies [N][K], fused qkv bias.
// ---------------------------------------------------------------------------
__global__ __launch_bounds__(256) void conv_weights_kernel(
    const float* __restrict__ Wq, const float* __restrict__ Wk, const float* __restrict__ Wv,
    const float* __restrict__ bq, const float* __restrict__ bk, const float* __restrict__ bv,
    const float* __restrict__ Wo, const float* __restrict__ Wf1, const float* __restrict__ Wf2,
    bf16* __restrict__ Wqkv_t, bf16* __restrict__ Wo_t, bf16* __restrict__ Wf1_t,
    bf16* __restrict__ Wf2_t, float* __restrict__ bqkv) {
  int i = blockIdx.x * 256 + threadIdx.x;
  if (i < 49152) {  // Wqkv_t [384][128]
    int n = i >> 7, k = i & 127;
    const float* W = (n < 128) ? Wq : ((n < 256) ? Wk : Wv);
    int nn = n & 127;
    Wqkv_t[i] = __float2bfloat16(W[k * 128 + nn]);
  } else if (i < 65536) {  // Wo_t [128][128]
    int j = i - 49152;
    int n = j >> 7, k = j & 127;
    Wo_t[j] = __float2bfloat16(Wo[k * 128 + n]);
  } else if (i < 98304) {  // Wf1_t [256][128]
    int j = i - 65536;
    int n = j >> 7, k = j & 127;
    Wf1_t[j] = __float2bfloat16(Wf1[k * 256 + n]);
  } else if (i < 131072) {  // Wf2_t [128][256]
    int j = i - 98304;
    int n = j >> 8, k = j & 255;
    Wf2_t[j] = __float2bfloat16(Wf2[k * 128 + n]);
  }
  if (i < 384) bqkv[i] = (i < 128) ? bq[i] : ((i < 256) ? bk[i - 128] : bv[i - 256]);
}

// ---------------------------------------------------------------------------
// LDS-free MFMA GEMM. C[M,Nc] = A[M,K] @ Wt^T + bias (+ epilogue).
// Wt is [Nc][K] bf16. Block 256 thr = 4 waves; wave w owns rows
// [bm+32w, bm+32w+32), block owns cols [bn, bn+64). K in {128, 256}.
// AF32: A is fp32 (converted in-register). EPI 0: none; 1: silu; 2: +R.
// OUTBF: write bf16 else fp32.
// ---------------------------------------------------------------------------
template <int K, int EPI, int OUTBF, int AF32>
__global__ __launch_bounds__(256) void mfma_gemm_kernel(
    const void* __restrict__ Ap, const bf16* __restrict__ Wt,
    const float* __restrict__ bias, const float* __restrict__ R,
    void* __restrict__ Cout, int M, int Nc) {
  const int tid = threadIdx.x;
  const int w = tid >> 6, l = tid & 63;
  const int lr = l & 15;  // row-in-frag (A) / col-in-frag (B,C)
  const int lk = l >> 4;  // k sub-block 0..3
  const int bm = blockIdx.x * 128, bn = blockIdx.y * 64;

  f32x4 acc[2][4] = {};
  const int arow0 = bm + w * 32 + lr;

  for (int k0 = 0; k0 < K; k0 += 128) {
    bf16x8 bfr[4][4];
#pragma unroll
    for (int fn = 0; fn < 4; ++fn) {
      const bf16* wp = Wt + (size_t)(bn + fn * 16 + lr) * K + k0 + lk * 8;
#pragma unroll
      for (int ks = 0; ks < 4; ++ks) bfr[fn][ks] = *(const bf16x8*)(wp + ks * 32);
    }
    bf16x8 afr[2][4];
#pragma unroll
    for (int fr = 0; fr < 2; ++fr) {
      int row = arow0 + fr * 16;
      if (row >= M) row = M - 1;
      if (AF32) {
        const float* ap = (const float*)Ap + (size_t)row * K + k0 + lk * 8;
#pragma unroll
        for (int ks = 0; ks < 4; ++ks) {
          float4 x = *(const float4*)(ap + ks * 32);
          float4 y = *(const float4*)(ap + ks * 32 + 4);
          bf16x8 t;
          t[0] = f2b(x.x); t[1] = f2b(x.y); t[2] = f2b(x.z); t[3] = f2b(x.w);
          t[4] = f2b(y.x); t[5] = f2b(y.y); t[6] = f2b(y.z); t[7] = f2b(y.w);
          afr[fr][ks] = t;
        }
      } else {
        const bf16* ap = (const bf16*)Ap + (size_t)row * K + k0 + lk * 8;
#pragma unroll
        for (int ks = 0; ks < 4; ++ks) afr[fr][ks] = *(const bf16x8*)(ap + ks * 32);
      }
    }
#pragma unroll
    for (int ks = 0; ks < 4; ++ks)
#pragma unroll
      for (int fr = 0; fr < 2; ++fr)
#pragma unroll
        for (int fn = 0; fn < 4; ++fn)
          acc[fr][fn] = __builtin_amdgcn_mfma_f32_16x16x32_bf16(afr[fr][ks], bfr[fn][ks],
                                                                acc[fr][fn], 0, 0, 0);
  }

#pragma unroll
  for (int fn = 0; fn < 4; ++fn) {
    const int col = bn + fn * 16 + lr;
    const float bv = bias[col];
#pragma unroll
    for (int fr = 0; fr < 2; ++fr) {
      const int rbase = bm + w * 32 + fr * 16 + lk * 4;
#pragma unroll
      for (int r = 0; r < 4; ++r) {
        int row = rbase + r;
        if (row < M) {
          float o = acc[fr][fn][r] + bv;
          if (EPI == 1) o = o / (1.f + __expf(-o));
          if (EPI == 2) o += R[(size_t)row * Nc + col];
          if (OUTBF)
            ((bf16*)Cout)[(size_t)row * Nc + col] = __float2bfloat16(o);
          else
            ((float*)Cout)[(size_t)row * Nc + col] = o;
        }
      }
    }
  }
}

// ---------------------------------------------------------------------------
// Edge bias MLP -> bf16 [E][8]
// ---------------------------------------------------------------------------
__global__ __launch_bounds__(256) void edge_bias_kernel(
    const float* __restrict__ ef, const float* __restrict__ Wb1,
    const float* __restrict__ bb1, const float* __restrict__ Wb2,
    const float* __restrict__ bb2, bf16* __restrict__ eb, int E) {
  __shared__ float w1[128], w2[64], b1[8], b2[8];
  int tid = threadIdx.x;
  if (tid < 128) w1[tid] = Wb1[tid];
  else if (tid < 192) w2[tid - 128] = Wb2[tid - 128];
  else if (tid < 200) b1[tid - 192] = bb1[tid - 192];
  else if (tid < 208) b2[tid - 200] = bb2[tid - 200];
  __syncthreads();

  int e = blockIdx.x * 256 + tid;
  if (e >= E) return;

  const float4* p4 = (const float4*)(ef + (size_t)e * 16);
  float4 f0 = p4[0], f1 = p4[1], f2 = p4[2], f3 = p4[3];
  float x[16] = {f0.x, f0.y, f0.z, f0.w, f1.x, f1.y, f1.z, f1.w,
                 f2.x, f2.y, f2.z, f2.w, f3.x, f3.y, f3.z, f3.w};

  float h[8];
#pragma unroll
  for (int j = 0; j < 8; ++j) h[j] = b1[j];
#pragma unroll
  for (int i = 0; i < 16; ++i) {
    float xi = x[i];
#pragma unroll
    for (int j = 0; j < 8; ++j) h[j] = fmaf(xi, w1[i * 8 + j], h[j]);
  }
#pragma unroll
  for (int j = 0; j < 8; ++j) h[j] = h[j] / (1.f + __expf(-h[j]));

  float o[8];
#pragma unroll
  for (int j = 0; j < 8; ++j) o[j] = b2[j];
#pragma unroll
  for (int jj = 0; jj < 8; ++jj) {
    float hj = h[jj];
#pragma unroll
    for (int j = 0; j < 8; ++j) o[j] = fmaf(hj, w2[jj * 8 + j], o[j]);
  }
  bf16x8 o8;
#pragma unroll
  for (int j = 0; j < 8; ++j) o8[j] = f2b(o[j]);
  *(bf16x8*)(eb + (size_t)e * 8) = o8;
}

// ---------------------------------------------------------------------------
// CSR build: histogram -> parallel 3-kernel scan -> scatter
// ---------------------------------------------------------------------------
__global__ void hist_kernel(const int* __restrict__ dst, int* __restrict__ counts, int E) {
  int e = blockIdx.x * blockDim.x + threadIdx.x;
  if (e < E) atomicAdd(&counts[dst[e]], 1);
}

__device__ __forceinline__ int wave_incl_scan(int x, int lane) {
  int incl = x;
#pragma unroll
  for (int off = 1; off < 64; off <<= 1) {
    int y = __shfl_up(incl, off, 64);
    if (lane >= off) incl += y;
  }
  return incl;
}

__global__ __launch_bounds__(256) void scan_block_kernel(const int* __restrict__ counts,
                                                         int* __restrict__ offs,
                                                         int* __restrict__ btot, int N) {
  __shared__ int s4[4];
  int tid = threadIdx.x;
  int i = blockIdx.x * 256 + tid;
  int lane = tid & 63, wv = tid >> 6;
  int x = (i < N) ? counts[i] : 0;
  int incl = wave_incl_scan(x, lane);
  if (lane == 63) s4[wv] = incl;
  __syncthreads();
  if (tid == 0) {
    int s = 0;
#pragma unroll
    for (int j = 0; j < 4; ++j) { int t = s4[j]; s4[j] = s; s += t; }
    btot[blockIdx.x] = s;
  }
  __syncthreads();
  if (i < N) offs[i] = s4[wv] + incl - x;
}

__global__ __launch_bounds__(256) void scan_tot_kernel(int* __restrict__ btot, int nb) {
  __shared__ int s4[4];
  __shared__ int carry;
  int tid = threadIdx.x;
  int lane = tid & 63, wv = tid >> 6;
  if (tid == 0) carry = 0;
  __syncthreads();
  for (int c0 = 0; c0 < nb; c0 += 256) {
    int i = c0 + tid;
    int x = (i < nb) ? btot[i] : 0;
    int incl = wave_incl_scan(x, lane);
    if (lane == 63) s4[wv] = incl;
    __syncthreads();
    if (tid == 0) {
      int s = 0;
#pragma unroll
      for (int j = 0; j < 4; ++j) { int t = s4[j]; s4[j] = s; s += t; }
    }
    __syncthreads();
    int base = carry + s4[wv];
    if (i < nb) btot[i] = base + incl - x;
    __syncthreads();
    if (tid == 255) carry = base + incl;
    __syncthreads();
  }
}

__global__ __launch_bounds__(256) void scan_add_kernel(int* __restrict__ offs,
                                                       const int* __restrict__ btot,
                                                       int N, int E) {
  int i = blockIdx.x * 256 + threadIdx.x;
  if (i < N) offs[i] += btot[blockIdx.x];
  if (i == 0) offs[N] = E;
}

__global__ void scatter_kernel(const int* __restrict__ dst, const int* __restrict__ src,
                               const int* __restrict__ offs, int* __restrict__ cursor,
                               int2* __restrict__ es_csr, int E) {
  int e = blockIdx.x * blockDim.x + threadIdx.x;
  if (e >= E) return;
  int d = dst[e];
  int p = offs[d] + atomicAdd(&cursor[d], 1);
  es_csr[p] = make_int2(e, src[e]);
}

// ---------------------------------------------------------------------------
// Attention: 1 wave per dst node, 4 edges in flight per wave.
// lane = g*16 + il ; g = edge slot 0..3 ; il owns cols il*8..il*8+7.
// qkv row: [q(128) | k(128) | v(128)] bf16, stride 384.
// ---------------------------------------------------------------------------
__global__ __launch_bounds__(256) void node_attn_kernel(
    const bf16* __restrict__ qkv, const int2* __restrict__ es_csr,
    const bf16* __restrict__ eb, const int* __restrict__ offs,
    bf16* __restrict__ agg, int Nn) {
  int n = blockIdx.x * 4 + (threadIdx.x >> 6);
  if (n >= Nn) return;
  int l = threadIdx.x & 63;
  int g = l >> 4;
  int il = l & 15;
  int head = il >> 1;

  bf16x8 q8 = *(const bf16x8*)(qkv + (size_t)n * 384 + il * 8);
  float qf[8];
#pragma unroll
  for (int j = 0; j < 8; ++j) qf[j] = b2f(q8[j]) * QK_SCALE;

  int s0 = offs[n], s1 = offs[n + 1];
  float m = -1e30f, lsum = 0.f;
  float acc[8] = {};

  for (int p0 = s0; p0 < s1; p0 += 4) {
    int p = p0 + g;
    bool valid = p < s1;
    int pc = valid ? p : s1 - 1;
    int2 es = es_csr[pc];
    const bf16* kvrow = qkv + (size_t)es.y * 384 + 128;
    bf16x8 k8 = *(const bf16x8*)(kvrow + il * 8);
    bf16x8 v8 = *(const bf16x8*)(kvrow + 128 + il * 8);
    float ebv = b2f(eb[(size_t)es.x * 8 + head]);

    float prod = 0.f;
#pragma unroll
    for (int j = 0; j < 8; ++j) prod = fmaf(qf[j], b2f(k8[j]), prod);
    prod += __shfl_xor(prod, 1, 64);

    float logit = valid ? (prod + ebv) : -3e38f;

    if (!__any(logit > m)) {
      // fast path: running max unchanged for every lane
      float pe = __expf(logit - m);  // invalid -> exp(-huge) = 0
      lsum += pe;
#pragma unroll
      for (int j = 0; j < 8; ++j) acc[j] = fmaf(pe, b2f(v8[j]), acc[j]);
    } else {
      float mnew = fmaxf(m, logit);
      float f = __expf(m - mnew);
      float pe = __expf(logit - mnew);
      lsum = lsum * f + pe;
#pragma unroll
      for (int j = 0; j < 8; ++j) acc[j] = fmaf(acc[j], f, pe * b2f(v8[j]));
      m = mnew;
    }
  }

  // merge 4 edge-slot partials (lanes xor 16, xor 32 share same cols)
#pragma unroll
  for (int off = 16; off < 64; off <<= 1) {
    float mo = __shfl_xor(m, off, 64);
    float lo = __shfl_xor(lsum, off, 64);
    float mn = fmaxf(m, mo);
    float fs = __expf(m - mn);
    float fo = __expf(mo - mn);
    lsum = lsum * fs + lo * fo;
#pragma unroll
    for (int j = 0; j < 8; ++j) {
      float ao = __shfl_xor(acc[j], off, 64);
      acc[j] = acc[j] * fs + ao * fo;
    }
    m = mn;
  }

  if (g == 0) {
    float inv = (lsum > 0.f) ? 1.f / lsum : 0.f;
    bf16x8 o8;
#pragma unroll
    for (int j = 0; j < 8; ++j) o8[j] = f2b(acc[j] * inv);
    *(bf16x8*)(agg + (size_t)n * HIDDEN + il * 8) = o8;
  }
}

// ---------------------------------------------------------------------------
// Row LayerNorm (128 cols). 1 wave/row, 4 rows/block. Optional bf16 copy out.
// ---------------------------------------------------------------------------
__global__ __launch_bounds__(256) void ln_kernel(const float* __restrict__ x,
                                                 const float* __restrict__ g,
                                                 const float* __restrict__ be,
                                                 float* __restrict__ y,
                                                 bf16* __restrict__ yb, int M) {
  int row = blockIdx.x * 4 + (threadIdx.x >> 6);
  int lane = threadIdx.x & 63;
  if (row >= M) return;
  float2 xv = *(const float2*)(x + (size_t)row * HIDDEN + lane * 2);
  float s = xv.x + xv.y;
  float sq = xv.x * xv.x + xv.y * xv.y;
#pragma unroll
  for (int off = 1; off < 64; off <<= 1) {
    s += __shfl_xor(s, off, 64);
    sq += __shfl_xor(sq, off, 64);
  }
  float mean = s * (1.f / 128.f);
  float var = sq * (1.f / 128.f) - mean * mean;
  float r = rsqrtf(var + LN_EPS);
  float2 gv = *(const float2*)(g + lane * 2);
  float2 bv = *(const float2*)(be + lane * 2);
  float2 yv;
  yv.x = (xv.x - mean) * r * gv.x + bv.x;
  yv.y = (xv.y - mean) * r * gv.y + bv.y;
  if (y) *(float2*)(y + (size_t)row * HIDDEN + lane * 2) = yv;
  if (yb) {
    __hip_bfloat162 h2;
    h2.x = __float2bfloat16(yv.x);
    h2.y = __float2bfloat16(yv.y);
    *(__hip_bfloat162*)(yb + (size_t)row * HIDDEN + lane * 2) = h2;
  }
}

// ---------------------------------------------------------------------------
extern "C" void kernel_launch(void* const* d_in, const int* in_sizes, int n_in,
                              void* d_out, int out_size, void* d_ws, size_t ws_size,
                              hipStream_t stream) {
  const float* nf = (const float*)d_in[0];
  const int* ei = (const int*)d_in[1];
  const float* ef = (const float*)d_in[2];
  const float* Wq = (const float*)d_in[3];
  const float* bq = (const float*)d_in[4];
  const float* Wk = (const float*)d_in[5];
  const float* bk_ = (const float*)d_in[6];
  const float* Wv = (const float*)d_in[7];
  const float* bv = (const float*)d_in[8];
  const float* Wb1 = (const float*)d_in[9];
  const float* bb1 = (const float*)d_in[10];
  const float* Wb2 = (const float*)d_in[11];
  const float* bb2 = (const float*)d_in[12];
  const float* Wo = (const float*)d_in[13];
  const float* bo = (const float*)d_in[14];
  const float* Wf1 = (const float*)d_in[15];
  const float* bf1 = (const float*)d_in[16];
  const float* Wf2 = (const float*)d_in[17];
  const float* bf2 = (const float*)d_in[18];
  const float* g1 = (const float*)d_in[19];
  const float* be1 = (const float*)d_in[20];
  const float* g2 = (const float*)d_in[21];
  const float* be2 = (const float*)d_in[22];

  const int N = in_sizes[0] / HIDDEN;
  const int E = in_sizes[2] / EDGE_DIM;
  const int* srcA = ei;
  const int* dstA = ei + E;

  char* base = (char*)d_ws;
  size_t off = 0;
  auto alloc = [&](size_t bytes) {
    off = (off + 255) & ~(size_t)255;
    char* p = base + off;
    off += bytes;
    return p;
  };

  // region B: qkv [N,384] bf16 -> hbuf [N,256] bf16
  bf16* qkv = (bf16*)alloc((size_t)N * 384 * 2);
  bf16* hbuf = qkv;
  // region C: eb [E,8] bf16 -> t1 [N,128] f32 -> t2 [N,128] f32
  size_t regC = (size_t)E * N_HEADS * 2;
  size_t t1b = (size_t)N * HIDDEN * 4;
  char* regCp = alloc(regC > t1b ? regC : t1b);
  bf16* eb = (bf16*)regCp;
  float* t1 = (float*)regCp;
  float* t2 = (float*)regCp;
  // standalone
  bf16* agg = (bf16*)alloc((size_t)N * HIDDEN * 2);
  float* x1 = (float*)alloc((size_t)N * HIDDEN * 4);
  bf16* x1b = (bf16*)alloc((size_t)N * HIDDEN * 2);
  int2* es_csr = (int2*)alloc((size_t)E * 8);
  int* counts = (int*)alloc((size_t)N * 4);
  int* offs = (int*)alloc((size_t)(N + 1) * 4);
  int* cursor = (int*)alloc((size_t)N * 4);
  const int nb = (N + 255) / 256;
  int* btot = (int*)alloc((size_t)nb * 4);
  // weights
  bf16* Wqkv_t = (bf16*)alloc(384 * 128 * 2);
  bf16* Wo_t = (bf16*)alloc(128 * 128 * 2);
  bf16* Wf1_t = (bf16*)alloc(256 * 128 * 2);
  bf16* Wf2_t = (bf16*)alloc(128 * 256 * 2);
  float* bqkv = (float*)alloc(384 * 4);

  float* outp = (float*)d_out;
  const int mb = (N + 127) / 128;
  const int eblocks = (E + 255) / 256;

  conv_weights_kernel<<<512, 256, 0, stream>>>(Wq, Wk, Wv, bq, bk_, bv, Wo, Wf1, Wf2,
                                               Wqkv_t, Wo_t, Wf1_t, Wf2_t, bqkv);

  // fused QKV projection (fp32 A, converted in-register) -> qkv bf16 [N][q|k|v]
  mfma_gemm_kernel<128, 0, 1, 1><<<dim3(mb, 6), 256, 0, stream>>>(
      nf, Wqkv_t, bqkv, nullptr, qkv, N, 384);

  // edge bias MLP (bf16 out)
  edge_bias_kernel<<<eblocks, 256, 0, stream>>>(ef, Wb1, bb1, Wb2, bb2, eb, E);

  // CSR build
  hipMemsetAsync(counts, 0, (size_t)N * 4, stream);
  hipMemsetAsync(cursor, 0, (size_t)N * 4, stream);
  hist_kernel<<<eblocks, 256, 0, stream>>>(dstA, counts, E);
  scan_block_kernel<<<nb, 256, 0, stream>>>(counts, offs, btot, N);
  scan_tot_kernel<<<1, 256, 0, stream>>>(btot, nb);
  scan_add_kernel<<<nb, 256, 0, stream>>>(offs, btot, N, E);
  scatter_kernel<<<eblocks, 256, 0, stream>>>(dstA, srcA, offs, cursor, es_csr, E);

  // attention + aggregation (4 edges in flight per wave)
  node_attn_kernel<<<(N + 3) / 4, 256, 0, stream>>>(qkv, es_csr, eb, offs, agg, N);

  // out proj + residual, LN1 (fp32 + bf16 copies)
  mfma_gemm_kernel<128, 2, 0, 0><<<dim3(mb, 2), 256, 0, stream>>>(
      agg, Wo_t, bo, nf, t1, N, 128);
  ln_kernel<<<(N + 3) / 4, 256, 0, stream>>>(t1, g1, be1, x1, x1b, N);

  // FFN
  mfma_gemm_kernel<128, 1, 1, 0><<<dim3(mb, 4), 256, 0, stream>>>(
      x1b, Wf1_t, bf1, nullptr, hbuf, N, 256);
  mfma_gemm_kernel<256, 2, 0, 0><<<dim3(mb, 2), 256, 0, stream>>>(
      hbuf, Wf2_t, bf2, x1, t2, N, 128);
  ln_kernel<<<(N + 3) / 4, 256, 0, stream>>>(t2, g2, be2, outp, nullptr, N);
}

// Round 4
// 298.351 us; speedup vs baseline: 1.9510x; 1.1806x over previous
//
#include <hip/hip_runtime.h>
#include <hip/hip_bf16.h>
#include <math.h>

#define HIDDEN 128
#define EDGE_DIM 16
#define N_HEADS 8
#define QK_SCALE 0.25f
#define LN_EPS 1e-5f

using bf16x8 = __attribute__((ext_vector_type(8))) short;
using f32x4 = __attribute__((ext_vector_type(4))) float;
typedef __hip_bfloat16 bf16;

__device__ __forceinline__ float b2f(short u) {
  union { unsigned int i; float f; } c;
  c.i = ((unsigned int)(unsigned short)u) << 16;
  return c.f;
}
__device__ __forceinline__ short f2b(float f) {
  bf16 h = __float2bfloat16(f);
  union { bf16 b; short s; } c;
  c.b = h;
  return c.s;
}

// ---------------------------------------------------------------------------
// Weight prep: transposed bf16 copies [N][K], fused qkv bias.
// ---------------------------------------------------------------------------
__global__ __launch_bounds__(256) void conv_weights_kernel(
    const float* __restrict__ Wq, const float* __restrict__ Wk, const float* __restrict__ Wv,
    const float* __restrict__ bq, const float* __restrict__ bk, const float* __restrict__ bv,
    const float* __restrict__ Wo, const float* __restrict__ Wf1, const float* __restrict__ Wf2,
    bf16* __restrict__ Wqkv_t, bf16* __restrict__ Wo_t, bf16* __restrict__ Wf1_t,
    bf16* __restrict__ Wf2_t, float* __restrict__ bqkv) {
  int i = blockIdx.x * 256 + threadIdx.x;
  if (i < 49152) {  // Wqkv_t [384][128]
    int n = i >> 7, k = i & 127;
    const float* W = (n < 128) ? Wq : ((n < 256) ? Wk : Wv);
    int nn = n & 127;
    Wqkv_t[i] = __float2bfloat16(W[k * 128 + nn]);
  } else if (i < 65536) {  // Wo_t [128][128]
    int j = i - 49152;
    int n = j >> 7, k = j & 127;
    Wo_t[j] = __float2bfloat16(Wo[k * 128 + n]);
  } else if (i < 98304) {  // Wf1_t [256][128]
    int j = i - 65536;
    int n = j >> 7, k = j & 127;
    Wf1_t[j] = __float2bfloat16(Wf1[k * 256 + n]);
  } else if (i < 131072) {  // Wf2_t [128][256]
    int j = i - 98304;
    int n = j >> 8, k = j & 255;
    Wf2_t[j] = __float2bfloat16(Wf2[k * 128 + n]);
  }
  if (i < 384) bqkv[i] = (i < 128) ? bq[i] : ((i < 256) ? bk[i - 128] : bv[i - 256]);
}

// ---------------------------------------------------------------------------
// MFMA GEMM, 64-row x 128-col block (4 waves = 2 row-halves x 2 col-halves).
// C[M,Nc] = A[M,K] @ Wt^T + bias (+ epilogue). Wt is [Nc][K] bf16.
// grid = (ceil(M/64), Nc/128). AF32: A fp32 converted in-register.
// EPI 0: none; 1: silu. OUTBF: bf16 out else fp32.
// ---------------------------------------------------------------------------
template <int K, int EPI, int OUTBF, int AF32>
__global__ __launch_bounds__(256) void mfma_gemm_kernel(
    const void* __restrict__ Ap, const bf16* __restrict__ Wt,
    const float* __restrict__ bias, void* __restrict__ Cout, int M, int Nc) {
  const int tid = threadIdx.x;
  const int w = tid >> 6, l = tid & 63;
  const int wr = w >> 1, wc = w & 1;
  const int lr = l & 15, lk = l >> 4;
  const int bm = blockIdx.x * 64;
  const int bn = blockIdx.y * 128 + wc * 64;

  f32x4 acc[2][4] = {};
  const int arow0 = bm + wr * 32 + lr;

  for (int k0 = 0; k0 < K; k0 += 128) {
    bf16x8 bfr[4][4];
#pragma unroll
    for (int fn = 0; fn < 4; ++fn) {
      const bf16* wp = Wt + (size_t)(bn + fn * 16 + lr) * K + k0 + lk * 8;
#pragma unroll
      for (int ks = 0; ks < 4; ++ks) bfr[fn][ks] = *(const bf16x8*)(wp + ks * 32);
    }
    bf16x8 afr[2][4];
#pragma unroll
    for (int fr = 0; fr < 2; ++fr) {
      int row = arow0 + fr * 16;
      if (row >= M) row = M - 1;
      if (AF32) {
        const float* ap = (const float*)Ap + (size_t)row * K + k0 + lk * 8;
#pragma unroll
        for (int ks = 0; ks < 4; ++ks) {
          float4 x = *(const float4*)(ap + ks * 32);
          float4 y = *(const float4*)(ap + ks * 32 + 4);
          bf16x8 t;
          t[0] = f2b(x.x); t[1] = f2b(x.y); t[2] = f2b(x.z); t[3] = f2b(x.w);
          t[4] = f2b(y.x); t[5] = f2b(y.y); t[6] = f2b(y.z); t[7] = f2b(y.w);
          afr[fr][ks] = t;
        }
      } else {
        const bf16* ap = (const bf16*)Ap + (size_t)row * K + k0 + lk * 8;
#pragma unroll
        for (int ks = 0; ks < 4; ++ks) afr[fr][ks] = *(const bf16x8*)(ap + ks * 32);
      }
    }
#pragma unroll
    for (int ks = 0; ks < 4; ++ks)
#pragma unroll
      for (int fr = 0; fr < 2; ++fr)
#pragma unroll
        for (int fn = 0; fn < 4; ++fn)
          acc[fr][fn] = __builtin_amdgcn_mfma_f32_16x16x32_bf16(afr[fr][ks], bfr[fn][ks],
                                                                acc[fr][fn], 0, 0, 0);
  }

#pragma unroll
  for (int fn = 0; fn < 4; ++fn) {
    const int col = bn + fn * 16 + lr;
    const float bv = bias[col];
#pragma unroll
    for (int fr = 0; fr < 2; ++fr) {
      const int rbase = bm + wr * 32 + fr * 16 + lk * 4;
#pragma unroll
      for (int r = 0; r < 4; ++r) {
        int row = rbase + r;
        if (row < M) {
          float o = acc[fr][fn][r] + bv;
          if (EPI == 1) o = o / (1.f + __expf(-o));
          if (OUTBF)
            ((bf16*)Cout)[(size_t)row * Nc + col] = __float2bfloat16(o);
          else
            ((float*)Cout)[(size_t)row * Nc + col] = o;
        }
      }
    }
  }
}

// ---------------------------------------------------------------------------
// MFMA GEMM + residual + LayerNorm fused. Nc = 128 fixed, block = 64 rows.
// out = LN(A @ Wt^T + bias + R) * gamma + beta. Writes y fp32 and/or yb bf16.
// ---------------------------------------------------------------------------
template <int K>
__global__ __launch_bounds__(256) void mfma_gemm_ln_kernel(
    const bf16* __restrict__ A, const bf16* __restrict__ Wt,
    const float* __restrict__ bias, const float* __restrict__ R,
    const float* __restrict__ gam, const float* __restrict__ bet,
    float* __restrict__ y, bf16* __restrict__ yb, int M) {
  const int tid = threadIdx.x;
  const int w = tid >> 6, l = tid & 63;
  const int wr = w >> 1, wc = w & 1;
  const int lr = l & 15, lk = l >> 4;
  const int bm = blockIdx.x * 64;
  const int bn = wc * 64;

  f32x4 acc[2][4] = {};
  const int arow0 = bm + wr * 32 + lr;

  for (int k0 = 0; k0 < K; k0 += 128) {
    bf16x8 bfr[4][4];
#pragma unroll
    for (int fn = 0; fn < 4; ++fn) {
      const bf16* wp = Wt + (size_t)(bn + fn * 16 + lr) * K + k0 + lk * 8;
#pragma unroll
      for (int ks = 0; ks < 4; ++ks) bfr[fn][ks] = *(const bf16x8*)(wp + ks * 32);
    }
    bf16x8 afr[2][4];
#pragma unroll
    for (int fr = 0; fr < 2; ++fr) {
      int row = arow0 + fr * 16;
      if (row >= M) row = M - 1;
      const bf16* ap = A + (size_t)row * K + k0 + lk * 8;
#pragma unroll
      for (int ks = 0; ks < 4; ++ks) afr[fr][ks] = *(const bf16x8*)(ap + ks * 32);
    }
#pragma unroll
    for (int ks = 0; ks < 4; ++ks)
#pragma unroll
      for (int fr = 0; fr < 2; ++fr)
#pragma unroll
        for (int fn = 0; fn < 4; ++fn)
          acc[fr][fn] = __builtin_amdgcn_mfma_f32_16x16x32_bf16(afr[fr][ks], bfr[fn][ks],
                                                                acc[fr][fn], 0, 0, 0);
  }

  // bias + residual into acc; per-row partial sums
  float bv[4], gv[4], ev[4];
#pragma unroll
  for (int fn = 0; fn < 4; ++fn) {
    int col = bn + fn * 16 + lr;
    bv[fn] = bias[col];
    gv[fn] = gam[col];
    ev[fn] = bet[col];
  }
  float ps[2][4], psq[2][4];
#pragma unroll
  for (int fr = 0; fr < 2; ++fr) {
#pragma unroll
    for (int r = 0; r < 4; ++r) {
      int row = bm + wr * 32 + fr * 16 + lk * 4 + r;
      int rrow = (row < M) ? row : (M - 1);
      float s = 0.f, sq = 0.f;
#pragma unroll
      for (int fn = 0; fn < 4; ++fn) {
        int col = bn + fn * 16 + lr;
        float o = acc[fr][fn][r] + bv[fn] + R[(size_t)rrow * HIDDEN + col];
        acc[fr][fn][r] = o;
        s += o;
        sq += o * o;
      }
      ps[fr][r] = s;
      psq[fr][r] = sq;
    }
  }
  // reduce across the 16 lanes of the lane-group (lr dimension)
#pragma unroll
  for (int off = 1; off < 16; off <<= 1) {
#pragma unroll
    for (int fr = 0; fr < 2; ++fr)
#pragma unroll
      for (int r = 0; r < 4; ++r) {
        ps[fr][r] += __shfl_xor(ps[fr][r], off, 64);
        psq[fr][r] += __shfl_xor(psq[fr][r], off, 64);
      }
  }
  __shared__ float s_sum[2][64], s_sq[2][64];
  if (lr == 0) {
#pragma unroll
    for (int fr = 0; fr < 2; ++fr)
#pragma unroll
      for (int r = 0; r < 4; ++r) {
        int rl = wr * 32 + fr * 16 + lk * 4 + r;
        s_sum[wc][rl] = ps[fr][r];
        s_sq[wc][rl] = psq[fr][r];
      }
  }
  __syncthreads();
#pragma unroll
  for (int fr = 0; fr < 2; ++fr) {
#pragma unroll
    for (int r = 0; r < 4; ++r) {
      int rl = wr * 32 + fr * 16 + lk * 4 + r;
      int row = bm + rl;
      float tot = s_sum[0][rl] + s_sum[1][rl];
      float tsq = s_sq[0][rl] + s_sq[1][rl];
      float mean = tot * (1.f / 128.f);
      float var = tsq * (1.f / 128.f) - mean * mean;
      float rstd = rsqrtf(var + LN_EPS);
      if (row < M) {
#pragma unroll
        for (int fn = 0; fn < 4; ++fn) {
          int col = bn + fn * 16 + lr;
          float val = (acc[fr][fn][r] - mean) * rstd * gv[fn] + ev[fn];
          if (y) y[(size_t)row * HIDDEN + col] = val;
          if (yb) yb[(size_t)row * HIDDEN + col] = __float2bfloat16(val);
        }
      }
    }
  }
}

// ---------------------------------------------------------------------------
// CSR build: histogram -> parallel 3-kernel scan -> fused scatter+edge-MLP
// ---------------------------------------------------------------------------
__global__ void hist_kernel(const int* __restrict__ dst, int* __restrict__ counts, int E) {
  int e = blockIdx.x * blockDim.x + threadIdx.x;
  if (e < E) atomicAdd(&counts[dst[e]], 1);
}

__device__ __forceinline__ int wave_incl_scan(int x, int lane) {
  int incl = x;
#pragma unroll
  for (int off = 1; off < 64; off <<= 1) {
    int y = __shfl_up(incl, off, 64);
    if (lane >= off) incl += y;
  }
  return incl;
}

__global__ __launch_bounds__(256) void scan_block_kernel(const int* __restrict__ counts,
                                                         int* __restrict__ offs,
                                                         int* __restrict__ btot, int N) {
  __shared__ int s4[4];
  int tid = threadIdx.x;
  int i = blockIdx.x * 256 + tid;
  int lane = tid & 63, wv = tid >> 6;
  int x = (i < N) ? counts[i] : 0;
  int incl = wave_incl_scan(x, lane);
  if (lane == 63) s4[wv] = incl;
  __syncthreads();
  if (tid == 0) {
    int s = 0;
#pragma unroll
    for (int j = 0; j < 4; ++j) { int t = s4[j]; s4[j] = s; s += t; }
    btot[blockIdx.x] = s;
  }
  __syncthreads();
  if (i < N) offs[i] = s4[wv] + incl - x;
}

__global__ __launch_bounds__(256) void scan_tot_kernel(int* __restrict__ btot, int nb) {
  __shared__ int s4[4];
  __shared__ int carry;
  int tid = threadIdx.x;
  int lane = tid & 63, wv = tid >> 6;
  if (tid == 0) carry = 0;
  __syncthreads();
  for (int c0 = 0; c0 < nb; c0 += 256) {
    int i = c0 + tid;
    int x = (i < nb) ? btot[i] : 0;
    int incl = wave_incl_scan(x, lane);
    if (lane == 63) s4[wv] = incl;
    __syncthreads();
    if (tid == 0) {
      int s = 0;
#pragma unroll
      for (int j = 0; j < 4; ++j) { int t = s4[j]; s4[j] = s; s += t; }
    }
    __syncthreads();
    int base = carry + s4[wv];
    if (i < nb) btot[i] = base + incl - x;
    __syncthreads();
    if (tid == 255) carry = base + incl;
    __syncthreads();
  }
}

__global__ __launch_bounds__(256) void scan_add_kernel(int* __restrict__ offs,
                                                       const int* __restrict__ btot,
                                                       int N, int E) {
  int i = blockIdx.x * 256 + threadIdx.x;
  if (i < N) offs[i] += btot[blockIdx.x];
  if (i == 0) offs[N] = E;
}

// scatter edges into CSR order; compute edge-bias MLP inline and write it
// (bf16 [8]) at the CSR slot, so the attention kernel reads it sequentially.
__global__ __launch_bounds__(256) void scatter_mlp_kernel(
    const int* __restrict__ dst, const int* __restrict__ src,
    const float* __restrict__ ef, const float* __restrict__ Wb1,
    const float* __restrict__ bb1, const float* __restrict__ Wb2,
    const float* __restrict__ bb2, const int* __restrict__ offs,
    int* __restrict__ cursor, int* __restrict__ src_csr,
    bf16* __restrict__ ebw, int E) {
  __shared__ float w1[128], w2[64], b1[8], b2[8];
  int tid = threadIdx.x;
  if (tid < 128) w1[tid] = Wb1[tid];
  else if (tid < 192) w2[tid - 128] = Wb2[tid - 128];
  else if (tid < 200) b1[tid - 192] = bb1[tid - 192];
  else if (tid < 208) b2[tid - 200] = bb2[tid - 200];
  __syncthreads();

  int e = blockIdx.x * 256 + tid;
  if (e >= E) return;

  const float4* p4 = (const float4*)(ef + (size_t)e * 16);
  float4 f0 = p4[0], f1 = p4[1], f2 = p4[2], f3 = p4[3];
  float x[16] = {f0.x, f0.y, f0.z, f0.w, f1.x, f1.y, f1.z, f1.w,
                 f2.x, f2.y, f2.z, f2.w, f3.x, f3.y, f3.z, f3.w};

  float h[8];
#pragma unroll
  for (int j = 0; j < 8; ++j) h[j] = b1[j];
#pragma unroll
  for (int i = 0; i < 16; ++i) {
    float xi = x[i];
#pragma unroll
    for (int j = 0; j < 8; ++j) h[j] = fmaf(xi, w1[i * 8 + j], h[j]);
  }
#pragma unroll
  for (int j = 0; j < 8; ++j) h[j] = h[j] / (1.f + __expf(-h[j]));

  float o[8];
#pragma unroll
  for (int j = 0; j < 8; ++j) o[j] = b2[j];
#pragma unroll
  for (int jj = 0; jj < 8; ++jj) {
    float hj = h[jj];
#pragma unroll
    for (int j = 0; j < 8; ++j) o[j] = fmaf(hj, w2[jj * 8 + j], o[j]);
  }
  bf16x8 o8;
#pragma unroll
  for (int j = 0; j < 8; ++j) o8[j] = f2b(o[j]);

  int d = dst[e];
  int p = offs[d] + atomicAdd(&cursor[d], 1);
  src_csr[p] = src[e];
  *(bf16x8*)(ebw + (size_t)p * 8) = o8;
}

// ---------------------------------------------------------------------------
// Attention: 1 wave per dst node, 4 edges in flight, NO max subtraction
// (logits are bounded by construction; exp is safe in fp32).
// lane = g*16 + il ; g = edge slot 0..3 ; il owns cols il*8..il*8+7.
// qkv row: [q(128) | k(128) | v(128)] bf16, stride 384.
// ---------------------------------------------------------------------------
__global__ __launch_bounds__(256) void node_attn_kernel(
    const bf16* __restrict__ qkv, const int* __restrict__ src_csr,
    const bf16* __restrict__ ebw, const int* __restrict__ offs,
    bf16* __restrict__ agg, int Nn) {
  int n = blockIdx.x * 4 + (threadIdx.x >> 6);
  if (n >= Nn) return;
  int l = threadIdx.x & 63;
  int g = l >> 4;
  int il = l & 15;
  int head = il >> 1;

  bf16x8 q8 = *(const bf16x8*)(qkv + (size_t)n * 384 + il * 8);
  float qf[8];
#pragma unroll
  for (int j = 0; j < 8; ++j) qf[j] = b2f(q8[j]) * QK_SCALE;

  int s0 = offs[n], s1 = offs[n + 1];
  float lsum = 0.f;
  float acc[8] = {};

  for (int p0 = s0; p0 < s1; p0 += 4) {
    int p = p0 + g;
    bool valid = p < s1;
    int pc = valid ? p : s1 - 1;
    int s = src_csr[pc];
    float ebv = b2f(ebw[(size_t)pc * 8 + head]);
    const bf16* kvrow = qkv + (size_t)s * 384 + 128;
    bf16x8 k8 = *(const bf16x8*)(kvrow + il * 8);
    bf16x8 v8 = *(const bf16x8*)(kvrow + 128 + il * 8);

    float prod = 0.f;
#pragma unroll
    for (int j = 0; j < 8; ++j) prod = fmaf(qf[j], b2f(k8[j]), prod);
    prod += __shfl_xor(prod, 1, 64);

    float pe = valid ? __expf(prod + ebv) : 0.f;
    lsum += pe;
#pragma unroll
    for (int j = 0; j < 8; ++j) acc[j] = fmaf(pe, b2f(v8[j]), acc[j]);
  }

  // sum 4 edge-slot partials (lanes xor 16, 32 share the same cols)
#pragma unroll
  for (int off = 16; off < 64; off <<= 1) {
    lsum += __shfl_xor(lsum, off, 64);
#pragma unroll
    for (int j = 0; j < 8; ++j) acc[j] += __shfl_xor(acc[j], off, 64);
  }

  if (g == 0) {
    float inv = (lsum > 0.f) ? 1.f / lsum : 0.f;
    bf16x8 o8;
#pragma unroll
    for (int j = 0; j < 8; ++j) o8[j] = f2b(acc[j] * inv);
    *(bf16x8*)(agg + (size_t)n * HIDDEN + il * 8) = o8;
  }
}

// ---------------------------------------------------------------------------
extern "C" void kernel_launch(void* const* d_in, const int* in_sizes, int n_in,
                              void* d_out, int out_size, void* d_ws, size_t ws_size,
                              hipStream_t stream) {
  const float* nf = (const float*)d_in[0];
  const int* ei = (const int*)d_in[1];
  const float* ef = (const float*)d_in[2];
  const float* Wq = (const float*)d_in[3];
  const float* bq = (const float*)d_in[4];
  const float* Wk = (const float*)d_in[5];
  const float* bk_ = (const float*)d_in[6];
  const float* Wv = (const float*)d_in[7];
  const float* bv = (const float*)d_in[8];
  const float* Wb1 = (const float*)d_in[9];
  const float* bb1 = (const float*)d_in[10];
  const float* Wb2 = (const float*)d_in[11];
  const float* bb2 = (const float*)d_in[12];
  const float* Wo = (const float*)d_in[13];
  const float* bo = (const float*)d_in[14];
  const float* Wf1 = (const float*)d_in[15];
  const float* bf1 = (const float*)d_in[16];
  const float* Wf2 = (const float*)d_in[17];
  const float* bf2 = (const float*)d_in[18];
  const float* g1 = (const float*)d_in[19];
  const float* be1 = (const float*)d_in[20];
  const float* g2 = (const float*)d_in[21];
  const float* be2 = (const float*)d_in[22];

  const int N = in_sizes[0] / HIDDEN;
  const int E = in_sizes[2] / EDGE_DIM;
  const int* srcA = ei;
  const int* dstA = ei + E;

  char* base = (char*)d_ws;
  size_t off = 0;
  auto alloc = [&](size_t bytes) {
    off = (off + 255) & ~(size_t)255;
    char* p = base + off;
    off += bytes;
    return p;
  };

  // region B: qkv [N,384] bf16 -> hbuf [N,256] bf16 (qkv dead after attn)
  bf16* qkv = (bf16*)alloc((size_t)N * 384 * 2);
  bf16* hbuf = qkv;
  // standalone
  bf16* agg = (bf16*)alloc((size_t)N * HIDDEN * 2);
  float* x1 = (float*)alloc((size_t)N * HIDDEN * 4);
  bf16* x1b = (bf16*)alloc((size_t)N * HIDDEN * 2);
  int* src_csr = (int*)alloc((size_t)E * 4);
  bf16* ebw = (bf16*)alloc((size_t)E * N_HEADS * 2);
  int* counts = (int*)alloc((size_t)N * 4);
  int* offs = (int*)alloc((size_t)(N + 1) * 4);
  int* cursor = (int*)alloc((size_t)N * 4);
  const int nb = (N + 255) / 256;
  int* btot = (int*)alloc((size_t)nb * 4);
  // weights
  bf16* Wqkv_t = (bf16*)alloc(384 * 128 * 2);
  bf16* Wo_t = (bf16*)alloc(128 * 128 * 2);
  bf16* Wf1_t = (bf16*)alloc(256 * 128 * 2);
  bf16* Wf2_t = (bf16*)alloc(128 * 256 * 2);
  float* bqkv = (float*)alloc(384 * 4);

  float* outp = (float*)d_out;
  const int mb64 = (N + 63) / 64;
  const int eblocks = (E + 255) / 256;

  conv_weights_kernel<<<512, 256, 0, stream>>>(Wq, Wk, Wv, bq, bk_, bv, Wo, Wf1, Wf2,
                                               Wqkv_t, Wo_t, Wf1_t, Wf2_t, bqkv);

  // fused QKV projection (fp32 A converted in-register) -> qkv bf16 [N][q|k|v]
  mfma_gemm_kernel<128, 0, 1, 1><<<dim3(mb64, 3), 256, 0, stream>>>(
      nf, Wqkv_t, bqkv, qkv, N, 384);

  // CSR build + fused edge-bias MLP scatter
  hipMemsetAsync(counts, 0, (size_t)N * 4, stream);
  hipMemsetAsync(cursor, 0, (size_t)N * 4, stream);
  hist_kernel<<<eblocks, 256, 0, stream>>>(dstA, counts, E);
  scan_block_kernel<<<nb, 256, 0, stream>>>(counts, offs, btot, N);
  scan_tot_kernel<<<1, 256, 0, stream>>>(btot, nb);
  scan_add_kernel<<<nb, 256, 0, stream>>>(offs, btot, N, E);
  scatter_mlp_kernel<<<eblocks, 256, 0, stream>>>(dstA, srcA, ef, Wb1, bb1, Wb2, bb2,
                                                  offs, cursor, src_csr, ebw, E);

  // attention + aggregation
  node_attn_kernel<<<(N + 3) / 4, 256, 0, stream>>>(qkv, src_csr, ebw, offs, agg, N);

  // out proj + residual + LN1 (fused) -> x1 fp32 + x1b bf16
  mfma_gemm_ln_kernel<128><<<mb64, 256, 0, stream>>>(agg, Wo_t, bo, nf, g1, be1, x1, x1b, N);

  // FFN1 (silu, bf16 out)
  mfma_gemm_kernel<128, 1, 1, 0><<<dim3(mb64, 2), 256, 0, stream>>>(
      x1b, Wf1_t, bf1, hbuf, N, 256);

  // FFN2 + residual + LN2 (fused) -> output fp32
  mfma_gemm_ln_kernel<256><<<mb64, 256, 0, stream>>>(hbuf, Wf2_t, bf2, x1, g2, be2,
                                                     outp, nullptr, N);
}